// Round 5
// baseline (181.252 us; speedup 1.0000x reference)
//
#include <hip/hip_runtime.h>
#include <hip/hip_bf16.h>

typedef unsigned short u16;
typedef __attribute__((ext_vector_type(8))) short  bf16x8;
typedef __attribute__((ext_vector_type(4))) float  fx4;

// flat offsets of TT cores in the packed kernel (reference iterates k=3..0 from idx 0)
#define OFF_C0 0       // core for k=3: [8 x 256]   core0[i4][a3*8+o4]
#define OFF_C1 2048    // core for k=2: [256 x 256] core1[i3*32+a3][a2*8+o3]
#define OFF_C2 67584   // core for k=1: [256 x 256] core2[i2*32+a2][a1*8+o2]
#define OFF_C3 133120  // core for k=0: [256 x 8]   core3[i1*32+a1][o1]

static __device__ __forceinline__ u16 f2bf(float f) {
  union { __hip_bfloat16 h; u16 u; } cv;
  cv.h = __float2bfloat16(f);
  return cv.u;
}
static __device__ __forceinline__ float bf2f(u16 u) {
  union { u16 u; __hip_bfloat16 h; } cv;
  cv.u = u;
  return __bfloat162float(cv.h);
}

// fused: blocks [0,8192) convert x fp32->bf16 (8 elems/thread); blocks [8192,8704) build W34T.
__global__ void x_and_w34T(const float* __restrict__ x, u16* __restrict__ xb,
                           const float* __restrict__ ker, float* __restrict__ w34T) {
  if (blockIdx.x < 8192) {
    int t = blockIdx.x * 256 + threadIdx.x;
    const fx4* p = (const fx4*)(x + (size_t)t * 8);
    fx4 v0 = p[0], v1 = p[1];
    u16 tmp[8];
#pragma unroll
    for (int q = 0; q < 4; ++q) tmp[q] = f2bf(v0[q]);
#pragma unroll
    for (int q = 0; q < 4; ++q) tmp[4 + q] = f2bf(v1[q]);
    typedef __attribute__((ext_vector_type(8))) u16 u16x8;
    *(u16x8*)(xb + (size_t)t * 8) = *(const u16x8*)tmp;
  } else {
    int t = (blockIdx.x - 8192) * 256 + threadIdx.x;   // 131072 threads
    int i34 = t & 63, c = t >> 6;
    int a2 = c >> 6, o3 = (c >> 3) & 7, o4 = c & 7;
    int i3 = i34 >> 3, i4 = i34 & 7;
    float s = 0.f;
#pragma unroll 8
    for (int a3 = 0; a3 < 32; ++a3) {
      float k1 = ker[OFF_C1 + (i3 * 32 + a3) * 256 + a2 * 8 + o3];
      float k0 = ker[OFF_C0 + i4 * 256 + a3 * 8 + o4];
      s += k1 * k0;
    }
    w34T[c * 64 + i34] = s;
  }
}

// W234t[(a1*64+o2*8+o3)*8 + o4][i234] = sum_a2 core2[i2*32+a2, a1*8+o2] * W34T[a2*64+o3*8+o4][i34]
__global__ void build_w234t2(const float* __restrict__ ker, const float* __restrict__ w34T,
                             u16* __restrict__ w234t) {
  int t = blockIdx.x * 256 + threadIdx.x;   // 131072 threads
  int i234 = t & 511, g = t >> 9;           // g = a1*8 + o3
  int a1 = g >> 3, o3 = g & 7;
  int i2 = i234 >> 6, i34 = i234 & 63;
  float acc[8][8];
#pragma unroll
  for (int a = 0; a < 8; ++a)
#pragma unroll
    for (int b = 0; b < 8; ++b) acc[a][b] = 0.f;
  for (int a2 = 0; a2 < 32; ++a2) {
    float w[8];
#pragma unroll
    for (int o4 = 0; o4 < 8; ++o4)
      w[o4] = w34T[(a2 * 64 + o3 * 8 + o4) * 64 + i34];
#pragma unroll
    for (int o2 = 0; o2 < 8; ++o2) {
      float c2 = ker[OFF_C2 + (i2 * 32 + a2) * 256 + a1 * 8 + o2];
#pragma unroll
      for (int o4 = 0; o4 < 8; ++o4) acc[o2][o4] += c2 * w[o4];
    }
  }
#pragma unroll
  for (int o2 = 0; o2 < 8; ++o2) {
    int cg = a1 * 64 + o2 * 8 + o3;
#pragma unroll
    for (int o4 = 0; o4 < 8; ++o4)
      w234t[(cg * 8 + o4) * 512 + i234] = f2bf(acc[o2][o4]);
  }
}

// Wt[j,i]: thread owns (j234, i234), reads each w234t element once, computes all 64 (i1,o1).
__global__ void build_wt2(const float* __restrict__ ker, const u16* __restrict__ w234t,
                          u16* __restrict__ wt) {
  int t = blockIdx.x * 256 + threadIdx.x;   // 262144 threads
  int i234 = t & 511, j234 = t >> 9;
  float acc[8][8];
#pragma unroll
  for (int a = 0; a < 8; ++a)
#pragma unroll
    for (int b = 0; b < 8; ++b) acc[a][b] = 0.f;
  for (int a1 = 0; a1 < 32; ++a1) {
    float w = bf2f(w234t[(a1 * 512 + j234) * 512 + i234]);
#pragma unroll
    for (int i1 = 0; i1 < 8; ++i1) {
      const float* c3 = ker + OFF_C3 + (i1 * 32 + a1) * 8;
#pragma unroll
      for (int o1 = 0; o1 < 8; ++o1) acc[i1][o1] += c3[o1] * w;
    }
  }
#pragma unroll
  for (int o1 = 0; o1 < 8; ++o1)
#pragma unroll
    for (int i1 = 0; i1 < 8; ++i1)
      wt[(size_t)(o1 * 512 + j234) * 4096 + i1 * 512 + i234] = f2bf(acc[i1][o1]);
}

__device__ __forceinline__ void gld16(const u16* g, u16* l) {
  __builtin_amdgcn_global_load_lds((const __attribute__((address_space(1))) void*)g,
                                   (__attribute__((address_space(3))) void*)l, 16, 0, 0);
}

// C[4096,4096] = A * Bt^T + bias (bf16 in, fp32 out), m201-style 8-phase schedule.
// BM=BN=256, BK=64/step (2 k-halves of 32), 8 waves (2Mx4N), per-wave 128x64 (8x4 frags 16x16x32).
// LDS: per operand 2 buf x 2 khalf x [256x32] bf16 (16KB units) = 128 KiB total.
// Per step, 4 phases: (kh0,m0-3 +B-kh0), (kh0,m4-7), (kh1,m0-3 +B-kh1), (kh1,m4-7).
// Each phase: ds_reads + stage 1 unit (2 gld16, 4 phases ahead) + barrier + lgkmcnt(0)
// + setprio(1) + 16 MFMA + setprio(0) + barrier. vmcnt(4) before closing barrier of ph1/ph3.
__global__ __launch_bounds__(512, 2) void gemm_8ph(const u16* __restrict__ Ag, const u16* __restrict__ Bg,
                                                   const float* __restrict__ bias, float* __restrict__ C) {
  __shared__ __align__(16) u16 sh[65536];  // A units [0,32768), B units [32768,65536)

  const int tid = threadIdx.x;
  const int lane = tid & 63;
  const int wave = tid >> 6;
  const int wm = wave >> 2, wn = wave & 3;
  const int fr = lane & 15, fg = lane >> 4;

  // XCD-aware block swizzle (256 blocks, 256%8==0)
  const int bid = blockIdx.x;
  const int wg = (bid & 7) * 32 + (bid >> 3);
  const int bm = (wg >> 4) * 256, bn = (wg & 15) * 256;

  // staging: thread -> row tid>>2 (+128 for 2nd load), slot tid&3 in a [256x32] unit;
  // LDS dest linear; global source slot pre-swizzled s ^ ((row>>1)&3)  (proven 0-conflict).
  const int srow = tid >> 2;
  const int sco = (((tid & 3) ^ ((tid >> 3) & 3)) * 8);
  const size_t agA0 = (size_t)(bm + srow) * 4096 + sco;
  const size_t agA1 = agA0 + (size_t)128 * 4096;
  const size_t agB0 = (size_t)(bn + srow) * 4096 + sco;
  const size_t agB1 = agB0 + (size_t)128 * 4096;
  const int ldsW = wave * 512;  // elements

#define ABASE(b, kh) (sh + ((b) * 2 + (kh)) * 8192)
#define BBASE(b, kh) (sh + 32768 + ((b) * 2 + (kh)) * 8192)
#define STAGE_A(b, kh, sp) do { const size_t c_ = (size_t)(((sp) & 63) * 64 + (kh) * 32); \
    gld16(Ag + agA0 + c_, ABASE(b, kh) + ldsW); \
    gld16(Ag + agA1 + c_, ABASE(b, kh) + ldsW + 4096); } while (0)
#define STAGE_B(b, kh, sp) do { const size_t c_ = (size_t)(((sp) & 63) * 64 + (kh) * 32); \
    gld16(Bg + agB0 + c_, BBASE(b, kh) + ldsW); \
    gld16(Bg + agB1 + c_, BBASE(b, kh) + ldsW + 4096); } while (0)

  // fragment element-offsets within a [256x32] unit: off = R*32 + ((fg ^ ((R>>1)&3))*8)
  int aoff[8], boff[4];
#pragma unroll
  for (int m = 0; m < 8; ++m) {
    const int R = wm * 128 + m * 16 + fr;
    aoff[m] = R * 32 + ((fg ^ ((R >> 1) & 3)) * 8);
  }
#pragma unroll
  for (int n = 0; n < 4; ++n) {
    const int R = wn * 64 + n * 16 + fr;
    boff[n] = R * 32 + ((fg ^ ((R >> 1) & 3)) * 8);
  }

  fx4 acc[8][4];
#pragma unroll
  for (int m = 0; m < 8; ++m)
#pragma unroll
    for (int n = 0; n < 4; ++n) acc[m][n] = (fx4){0.f, 0.f, 0.f, 0.f};

  // prologue: stage step 0's 4 units (order A-kh0, B-kh0, A-kh1, B-kh1); wait oldest 2 units.
  STAGE_A(0, 0, 0);
  STAGE_B(0, 0, 0);
  STAGE_A(0, 1, 0);
  STAGE_B(0, 1, 0);
  asm volatile("s_waitcnt vmcnt(4)" ::: "memory");
  __builtin_amdgcn_s_barrier();

  auto kstep = [&](const int b, const int s) {
    const int nb = 1 - b;
    bf16x8 av[4], bv[4];
    // ---- phase 0: kh0, m0-3 (+ all B kh0) ----
#pragma unroll
    for (int m = 0; m < 4; ++m) av[m] = *(const bf16x8*)(ABASE(b, 0) + aoff[m]);
#pragma unroll
    for (int n = 0; n < 4; ++n) bv[n] = *(const bf16x8*)(BBASE(b, 0) + boff[n]);
    STAGE_A(nb, 0, s + 1);
    __builtin_amdgcn_s_barrier();
    asm volatile("s_waitcnt lgkmcnt(0)" ::: "memory");
    __builtin_amdgcn_s_setprio(1);
#pragma unroll
    for (int m = 0; m < 4; ++m)
#pragma unroll
      for (int n = 0; n < 4; ++n)
        acc[m][n] = __builtin_amdgcn_mfma_f32_16x16x32_bf16(av[m], bv[n], acc[m][n], 0, 0, 0);
    __builtin_amdgcn_s_setprio(0);
    __builtin_amdgcn_s_barrier();
    // ---- phase 1: kh0, m4-7 (bv reused) ----
#pragma unroll
    for (int m = 0; m < 4; ++m) av[m] = *(const bf16x8*)(ABASE(b, 0) + aoff[4 + m]);
    STAGE_B(nb, 0, s + 1);
    __builtin_amdgcn_s_barrier();
    asm volatile("s_waitcnt lgkmcnt(0)" ::: "memory");
    __builtin_amdgcn_s_setprio(1);
#pragma unroll
    for (int m = 0; m < 4; ++m)
#pragma unroll
      for (int n = 0; n < 4; ++n)
        acc[4 + m][n] = __builtin_amdgcn_mfma_f32_16x16x32_bf16(av[m], bv[n], acc[4 + m][n], 0, 0, 0);
    __builtin_amdgcn_s_setprio(0);
    asm volatile("s_waitcnt vmcnt(4)" ::: "memory");  // retire A-kh1(s), B-kh1(s)
    __builtin_amdgcn_s_barrier();
    // ---- phase 2: kh1, m0-3 (+ all B kh1) ----
#pragma unroll
    for (int m = 0; m < 4; ++m) av[m] = *(const bf16x8*)(ABASE(b, 1) + aoff[m]);
#pragma unroll
    for (int n = 0; n < 4; ++n) bv[n] = *(const bf16x8*)(BBASE(b, 1) + boff[n]);
    STAGE_A(nb, 1, s + 1);
    __builtin_amdgcn_s_barrier();
    asm volatile("s_waitcnt lgkmcnt(0)" ::: "memory");
    __builtin_amdgcn_s_setprio(1);
#pragma unroll
    for (int m = 0; m < 4; ++m)
#pragma unroll
      for (int n = 0; n < 4; ++n)
        acc[m][n] = __builtin_amdgcn_mfma_f32_16x16x32_bf16(av[m], bv[n], acc[m][n], 0, 0, 0);
    __builtin_amdgcn_s_setprio(0);
    __builtin_amdgcn_s_barrier();
    // ---- phase 3: kh1, m4-7 ----
#pragma unroll
    for (int m = 0; m < 4; ++m) av[m] = *(const bf16x8*)(ABASE(b, 1) + aoff[4 + m]);
    STAGE_B(nb, 1, s + 1);
    __builtin_amdgcn_s_barrier();
    asm volatile("s_waitcnt lgkmcnt(0)" ::: "memory");
    __builtin_amdgcn_s_setprio(1);
#pragma unroll
    for (int m = 0; m < 4; ++m)
#pragma unroll
      for (int n = 0; n < 4; ++n)
        acc[4 + m][n] = __builtin_amdgcn_mfma_f32_16x16x32_bf16(av[m], bv[n], acc[4 + m][n], 0, 0, 0);
    __builtin_amdgcn_s_setprio(0);
    asm volatile("s_waitcnt vmcnt(4)" ::: "memory");  // retire A-kh0(s+1), B-kh0(s+1)
    __builtin_amdgcn_s_barrier();
  };

  for (int it = 0; it < 32; ++it) {
    kstep(0, it * 2);
    kstep(1, it * 2 + 1);
  }

  // epilogue: C/D layout col=lane&15, row=(lane>>4)*4+reg  [m89]
  const int crow0 = bm + wm * 128 + fg * 4;
  const int ccol0 = bn + wn * 64 + fr;
#pragma unroll
  for (int n = 0; n < 4; ++n) {
    const int col = ccol0 + n * 16;
    const float bvl = bias[col];
#pragma unroll
    for (int mf = 0; mf < 8; ++mf) {
      const int r0 = crow0 + mf * 16;
#pragma unroll
      for (int q = 0; q < 4; ++q)
        C[(size_t)(r0 + q) * 4096 + col] = acc[mf][n][q] + bvl;
    }
  }
#undef ABASE
#undef BBASE
#undef STAGE_A
#undef STAGE_B
}

extern "C" void kernel_launch(void* const* d_in, const int* in_sizes, int n_in,
                              void* d_out, int out_size, void* d_ws, size_t ws_size,
                              hipStream_t stream) {
  const float* x    = (const float*)d_in[0];
  const float* ker  = (const float*)d_in[1];
  const float* bias = (const float*)d_in[2];
  float* out = (float*)d_out;

  char* ws = (char*)d_ws;
  u16*  xb    = (u16*)ws;                      // 32 MB  bf16 x
  u16*  wt    = (u16*)(ws + 33554432);         // 32 MB  bf16 W^T
  u16*  w234t = (u16*)(ws + 67108864);         // 16 MB  bf16 W234^T
  float* w34T = (float*)(ws + 83886080);       // 512 KB fp32 W34 transposed

  x_and_w34T  <<<8704, 256, 0, stream>>>(x, xb, ker, w34T);
  build_w234t2<<<512, 256, 0, stream>>>(ker, w34T, w234t);
  build_wt2   <<<1024, 256, 0, stream>>>(ker, w234t, wt);
  gemm_8ph    <<<256, 512, 0, stream>>>(xb, wt, bias, out);
}